// Round 2
// baseline (271.346 us; speedup 1.0000x reference)
//
#include <hip/hip_runtime.h>
#include <stdint.h>

#define NR 8192
#define DE 1024
#define DC 512
#define BIGF 9999999.0f
#define MARG 0.3f
#define NEGI -3.0e38f
#define POSI 3.0e38f

typedef __attribute__((ext_vector_type(8))) short bf16x8;
typedef __attribute__((ext_vector_type(4))) float f32x4;

typedef __attribute__((address_space(3))) unsigned int lds_u32;
typedef const __attribute__((address_space(1))) unsigned int glb_u32;

static __device__ __forceinline__ void ld_g2l16(const void* g, void* l) {
    __builtin_amdgcn_global_load_lds((glb_u32*)g, (lds_u32*)l, 16, 0, 0);
}

static __device__ __forceinline__ unsigned short f2bf(float x) {
    unsigned u = __float_as_uint(x);
    unsigned r = u + 0x7FFFu + ((u >> 16) & 1u);
    return (unsigned short)(r >> 16);
}

static __device__ __forceinline__ float b2f(short u) {
    return __uint_as_float(((unsigned)(unsigned short)u) << 16);
}

// ---------------- K1: emb -> bf16, sq[i] = ||emb_i||^2, class histogram ----------------
__global__ __launch_bounds__(256) void k_prep_emb(const float* __restrict__ emb,
                                                  const int* __restrict__ label,
                                                  short* __restrict__ embb,
                                                  float* __restrict__ sq,
                                                  int* __restrict__ cnt) {
    int row = blockIdx.x, tid = threadIdx.x;
    float4 v = ((const float4*)(emb + (size_t)row * DE))[tid];
    float s = v.x * v.x + v.y * v.y + v.z * v.z + v.w * v.w;
    ushort4 b;
    b.x = f2bf(v.x); b.y = f2bf(v.y); b.z = f2bf(v.z); b.w = f2bf(v.w);
    *(ushort4*)&embb[(size_t)row * DE + tid * 4] = b;
    for (int m = 1; m < 64; m <<= 1) s += __shfl_xor(s, m);
    __shared__ float red[4];
    if ((tid & 63) == 0) red[tid >> 6] = s;
    __syncthreads();
    if (tid == 0) {
        sq[row] = red[0] + red[1] + red[2] + red[3];
        atomicAdd(&cnt[label[row]], 1);
    }
}

// ---------------- K2: exclusive scan of class counts (512, single block) ----------------
__global__ __launch_bounds__(512) void k_scan(const int* __restrict__ cnt,
                                              int* __restrict__ clsOff) {
    __shared__ int s[512];
    int t = threadIdx.x;
    s[t] = cnt[t];
    __syncthreads();
    for (int d = 1; d < 512; d <<= 1) {
        int v = (t >= d) ? s[t - d] : 0;
        __syncthreads();
        s[t] += v;
        __syncthreads();
    }
    clsOff[t] = s[t] - cnt[t];
}

// ---------------- K3: scatter rows into class member lists ----------------
__global__ __launch_bounds__(256) void k_fill(const int* __restrict__ label,
                                              const int* __restrict__ clsOff,
                                              int* __restrict__ fill,
                                              int* __restrict__ list) {
    int i = blockIdx.x * 256 + threadIdx.x;
    int l = label[i];
    int p = atomicAdd(&fill[l], 1);
    list[clsOff[l] + p] = i;
}

// ---------------- K4: symmetric GEMM + min-of-negative row & column reductions ----------------
// m201-style 256^2 8-wave 4-phase-per-K-tile template (T2+T3+T4+T5):
//  - 528 upper-tri blocks (pr<=pc, 256-row x 256-col panels), 512 threads = 8 waves (2M x 4N),
//    per-wave 128x64 output = acc[8][4] (same fragment layout as previous passing kernel).
//  - LDS 128KB: As[2dbuf][2half][128x64], Bs same. 1 block/CU, 8 waves/CU.
//  - per K-tile (BK=64): 4 phases, each {ds_read frag subtile | stage one 16KB half-tile of
//    kt+1 into buf^1 (2 gload_lds/thread) | barrier | lgkmcnt(0)+sched_barrier | setprio(1)
//    16 MFMA setprio(0) | barrier}. ONE vmcnt(2) per K-tile (phase 0); never 0 until kt=15.
//  - race-freedom: buf^1's last readers are kt-1; per-phase barriers bound skew, so all
//    buf[b] ds_reads retire (ph2 lgkm) before any wave passes ph3's barrier and issues
//    kt+1 staging. ph0 reads come AFTER the vmcnt+barrier (staging of kt visible).
//  - swizzle (rule #21, both sides): LDS slot (r,s) holds global chunk g = s ^ ((r>>1)&3);
//    gload_lds dest stays LINEAR (byte t*16 / 8192+t*16), inverse permute applied on the
//    global SOURCE address. Read quad = 4(l15&1) + (q^((l15>>1)&3)) -> 2 lanes/quad = free.
__global__ __launch_bounds__(512, 2) void k_main(const short* __restrict__ embb,
                                                 const float* __restrict__ sq,
                                                 const int* __restrict__ label,
                                                 unsigned* __restrict__ mnA) {
    int L = blockIdx.x, pr = 0, rem = L;
    while (rem >= 32 - pr) { rem -= 32 - pr; ++pr; }
    const int pc = pr + rem;
    const int i0 = pr * 256, j0 = pc * 256;

    __shared__ __align__(16) short As[2][2][8192];
    __shared__ __align__(16) short Bs[2][2][8192];

    const int tid = threadIdx.x;
    const int lane = tid & 63;
    const int w = tid >> 6;
    const int wr = w >> 2, wc = w & 3;
    const int q = lane >> 4, l15 = lane & 15;

    // staging: thread t -> slot row r = t>>2, slot chunks {c, c+4}, c = t&3.
    // source global chunk for slot s: g = s ^ ((r>>1)&3); here g1 = (t&3) ^ ((t>>3)&3).
    const int sr = tid >> 2;
    const int g1 = (tid & 3) ^ ((tid >> 3) & 3);
    const short* gA = embb + (size_t)(i0 + sr) * DE + g1 * 8;
    const short* gB = embb + (size_t)(j0 + sr) * DE + g1 * 8;
    const int t8 = tid * 8;

    // fragment read offset (shorts): row (16*m + l15) * 32sh, chunk (q ^ ((l15>>1)&3)) * 8sh
    const int fx = l15 * 32 + ((q ^ ((l15 >> 1) & 3)) * 8);
    const int bh = wc >> 1, bo = (wc & 1) * 2048;

    f32x4 acc[8][4];
#pragma unroll
    for (int m = 0; m < 8; ++m)
#pragma unroll
        for (int n = 0; n < 4; ++n) acc[m][n] = (f32x4){0.f, 0.f, 0.f, 0.f};

    auto stA = [&](int half, int ko, int b) {
        const short* s = gA + (size_t)half * 128 * DE + ko;
        ld_g2l16(s, &As[b][half][t8]);
        ld_g2l16(s + 32, &As[b][half][4096 + t8]);
    };
    auto stB = [&](int half, int ko, int b) {
        const short* s = gB + (size_t)half * 128 * DE + ko;
        ld_g2l16(s, &Bs[b][half][t8]);
        ld_g2l16(s + 32, &Bs[b][half][4096 + t8]);
    };

    // prologue: all 4 halves of kt=0 -> buf0 (8 loads/wave outstanding)
    stA(0, 0, 0); stA(1, 0, 0); stB(0, 0, 0); stB(1, 0, 0);

    for (int kt = 0; kt < 16; ++kt) {
        const int b = kt & 1, nb = b ^ 1;
        const bool pf = kt < 15;
        const int ko = (kt + 1) * 64;

        bf16x8 a0[8], a1[8], b0[4], b1[4];

        // ---------- phase 0: (mh0, nh0) ----------
        if (pf) {
            stA(0, ko, nb);
            asm volatile("s_waitcnt vmcnt(2)" ::: "memory");
        } else {
            asm volatile("s_waitcnt vmcnt(0)" ::: "memory");
        }
        asm volatile("s_barrier" ::: "memory");
#pragma unroll
        for (int kk = 0; kk < 2; ++kk)
#pragma unroll
            for (int mm = 0; mm < 4; ++mm)
                a0[kk * 4 + mm] = *(const bf16x8*)&As[b][wr][kk * 4096 + mm * 512 + fx];
#pragma unroll
        for (int kk = 0; kk < 2; ++kk)
#pragma unroll
            for (int nn = 0; nn < 2; ++nn)
                b0[kk * 2 + nn] = *(const bf16x8*)&Bs[b][bh][kk * 4096 + bo + nn * 512 + fx];
        asm volatile("s_waitcnt lgkmcnt(0)" ::: "memory");
        __builtin_amdgcn_sched_barrier(0);
        __builtin_amdgcn_s_setprio(1);
#pragma unroll
        for (int kk = 0; kk < 2; ++kk)
#pragma unroll
            for (int mm = 0; mm < 4; ++mm)
#pragma unroll
                for (int nn = 0; nn < 2; ++nn)
                    acc[mm][nn] = __builtin_amdgcn_mfma_f32_16x16x32_bf16(a0[kk * 4 + mm], b0[kk * 2 + nn], acc[mm][nn], 0, 0, 0);
        __builtin_amdgcn_s_setprio(0);
        asm volatile("s_barrier" ::: "memory");

        // ---------- phase 1: (mh0, nh1) ----------
#pragma unroll
        for (int kk = 0; kk < 2; ++kk)
#pragma unroll
            for (int nn = 0; nn < 2; ++nn)
                b1[kk * 2 + nn] = *(const bf16x8*)&Bs[b][bh][kk * 4096 + bo + (2 + nn) * 512 + fx];
        if (pf) stA(1, ko, nb);
        asm volatile("s_barrier" ::: "memory");
        asm volatile("s_waitcnt lgkmcnt(0)" ::: "memory");
        __builtin_amdgcn_sched_barrier(0);
        __builtin_amdgcn_s_setprio(1);
#pragma unroll
        for (int kk = 0; kk < 2; ++kk)
#pragma unroll
            for (int mm = 0; mm < 4; ++mm)
#pragma unroll
                for (int nn = 0; nn < 2; ++nn)
                    acc[mm][2 + nn] = __builtin_amdgcn_mfma_f32_16x16x32_bf16(a0[kk * 4 + mm], b1[kk * 2 + nn], acc[mm][2 + nn], 0, 0, 0);
        __builtin_amdgcn_s_setprio(0);
        asm volatile("s_barrier" ::: "memory");

        // ---------- phase 2: (mh1, nh0) ----------
#pragma unroll
        for (int kk = 0; kk < 2; ++kk)
#pragma unroll
            for (int mm = 0; mm < 4; ++mm)
                a1[kk * 4 + mm] = *(const bf16x8*)&As[b][wr][kk * 4096 + (4 + mm) * 512 + fx];
        if (pf) stB(0, ko, nb);
        asm volatile("s_barrier" ::: "memory");
        asm volatile("s_waitcnt lgkmcnt(0)" ::: "memory");
        __builtin_amdgcn_sched_barrier(0);
        __builtin_amdgcn_s_setprio(1);
#pragma unroll
        for (int kk = 0; kk < 2; ++kk)
#pragma unroll
            for (int mm = 0; mm < 4; ++mm)
#pragma unroll
                for (int nn = 0; nn < 2; ++nn)
                    acc[4 + mm][nn] = __builtin_amdgcn_mfma_f32_16x16x32_bf16(a1[kk * 4 + mm], b0[kk * 2 + nn], acc[4 + mm][nn], 0, 0, 0);
        __builtin_amdgcn_s_setprio(0);
        asm volatile("s_barrier" ::: "memory");

        // ---------- phase 3: (mh1, nh1) ----------
        if (pf) stB(1, ko, nb);
        asm volatile("s_barrier" ::: "memory");
        __builtin_amdgcn_s_setprio(1);
#pragma unroll
        for (int kk = 0; kk < 2; ++kk)
#pragma unroll
            for (int mm = 0; mm < 4; ++mm)
#pragma unroll
                for (int nn = 0; nn < 2; ++nn)
                    acc[4 + mm][2 + nn] = __builtin_amdgcn_mfma_f32_16x16x32_bf16(a1[kk * 4 + mm], b1[kk * 2 + nn], acc[4 + mm][2 + nn], 0, 0, 0);
        __builtin_amdgcn_s_setprio(0);
        asm volatile("s_barrier" ::: "memory");
    }

    // ---- epilogue: masked d2, row-min (registers+butterfly) & col-min -> atomicMin ----
    // diagonal-overlap tiles double-count pairs: harmless for min. self-pair masked by label.
    const int rb = i0 + wr * 128;
    const int cb = j0 + wc * 64;
    float sqj[4]; int lbj[4];
#pragma unroll
    for (int n = 0; n < 4; ++n) {
        int cg = cb + n * 16 + l15;
        sqj[n] = sq[cg]; lbj[n] = label[cg];
    }
    float cmn[4] = {POSI, POSI, POSI, POSI};
#pragma unroll
    for (int m = 0; m < 8; ++m) {
        float rm[4] = {POSI, POSI, POSI, POSI};
        float sqi[4]; int lbi[4];
#pragma unroll
        for (int rr = 0; rr < 4; ++rr) {
            int rg = rb + m * 16 + q * 4 + rr;
            sqi[rr] = sq[rg]; lbi[rr] = label[rg];
        }
#pragma unroll
        for (int n = 0; n < 4; ++n)
#pragma unroll
            for (int rr = 0; rr < 4; ++rr) {
                float d2 = fmaf(-2.0f, acc[m][n][rr], sqi[rr] + sqj[n]);
                d2 = fmaxf(d2, 1e-12f);
                float dn = (lbi[rr] == lbj[n]) ? POSI : d2;
                rm[rr] = fminf(rm[rr], dn);
                cmn[n] = fminf(cmn[n], dn);
            }
#pragma unroll
        for (int rr = 0; rr < 4; ++rr) {
            float v = rm[rr];
            v = fminf(v, __shfl_xor(v, 1));
            v = fminf(v, __shfl_xor(v, 2));
            v = fminf(v, __shfl_xor(v, 4));
            v = fminf(v, __shfl_xor(v, 8));
            if (l15 == 0) atomicMin(&mnA[rb + m * 16 + q * 4 + rr], __float_as_uint(v));
        }
    }
#pragma unroll
    for (int n = 0; n < 4; ++n) {
        float v = cmn[n];
        v = fminf(v, __shfl_xor(v, 16));
        v = fminf(v, __shfl_xor(v, 32));
        if (q == 0) atomicMin(&mnA[cb + n * 16 + l15], __float_as_uint(v));
    }
}

// ---------------- K5: exact per-row positives (top-2 over classmates) + alphas ----------------
__global__ __launch_bounds__(256) void k_pos(const short* __restrict__ embb,
                                             const float* __restrict__ sq,
                                             const float* __restrict__ clot,
                                             const int* __restrict__ label,
                                             const int* __restrict__ cnt,
                                             const int* __restrict__ clsOff,
                                             const int* __restrict__ clsList,
                                             const unsigned* __restrict__ mnA,
                                             float* __restrict__ ap1, float* __restrict__ ap2,
                                             float* __restrict__ an,
                                             float* __restrict__ alpha1, float* __restrict__ alpha2) {
    int wid = threadIdx.x >> 6, lane = threadIdx.x & 63;
    int row = blockIdx.x * 4 + wid;
    int lb = label[row];
    int cc = cnt[lb], off = clsOff[lb];
    float sqiv = sq[row];

    const bf16x8* rp = (const bf16x8*)(embb + (size_t)row * DE + lane * 16);
    bf16x8 ra = rp[0], rb = rp[1];
    float rf[16];
#pragma unroll
    for (int t = 0; t < 8; ++t) { rf[t] = b2f(ra[t]); rf[8 + t] = b2f(rb[t]); }

    float v1 = NEGI, v2 = NEGI;
    int i1 = 0, i2 = 0;
    for (int m = 0; m < cc; ++m) {
        int j = clsList[off + m];
        float d2;
        if (j == row) {
            d2 = 1e-12f;
        } else {
            const bf16x8* jp = (const bf16x8*)(embb + (size_t)j * DE + lane * 16);
            bf16x8 ja = jp[0], jb = jp[1];
            float s = 0.f;
#pragma unroll
            for (int t = 0; t < 8; ++t) s = fmaf(rf[t], b2f(ja[t]), s);
#pragma unroll
            for (int t = 0; t < 8; ++t) s = fmaf(rf[8 + t], b2f(jb[t]), s);
            for (int mm = 1; mm < 64; mm <<= 1) s += __shfl_xor(s, mm);
            d2 = fmaxf(fmaf(-2.0f, s, sqiv + sq[j]), 1e-12f);
        }
        bool t1 = (d2 > v1) || (d2 == v1 && j < i1);
        bool t2 = (d2 > v2) || (d2 == v2 && j < i2);
        v2 = t1 ? v1 : (t2 ? d2 : v2);
        i2 = t1 ? i1 : (t2 ? j : i2);
        v1 = t1 ? d2 : v1;
        i1 = t1 ? j : i1;
    }

    float a1 = sqrtf(v1);
    int j1 = i1;
    float a2v; int j2;
    if (cc >= 2) {
        a2v = sqrtf(v2);
        j2 = i2;
    } else {
        // singleton class: ref falls back to best (max-dist) negative - BIG
        float kv = NEGI; int ki = 0;
        for (int c = lane; c < NR; c += 64) {
            if (label[c] == lb) continue;
            float s = 0.f;
            const short* crow = embb + (size_t)c * DE;
            const short* rrow = embb + (size_t)row * DE;
            for (int t = 0; t < DE; ++t) s = fmaf(b2f(rrow[t]), b2f(crow[t]), s);
            float d2c = fmaxf(fmaf(-2.0f, s, sqiv + sq[c]), 1e-12f);
            bool tk = (d2c > kv) || (d2c == kv && c < ki);
            kv = tk ? d2c : kv; ki = tk ? c : ki;
        }
        for (int mm = 1; mm < 64; mm <<= 1) {
            float ov = __shfl_xor(kv, mm); int oi = __shfl_xor(ki, mm);
            bool tk = (ov > kv) || (ov == kv && oi < ki);
            kv = tk ? ov : kv; ki = tk ? oi : ki;
        }
        a2v = sqrtf(kv) - BIGF;
        j2 = ki;
    }

    // alpha dots + norms over clot
    const float4* c4 = (const float4*)clot;
    float s1 = 0.f, s2 = 0.f, n0 = 0.f, n1 = 0.f, n2 = 0.f;
    for (int t = lane; t < DC / 4; t += 64) {
        float4 a = c4[(size_t)row * (DC / 4) + t];
        float4 b1 = c4[(size_t)j1 * (DC / 4) + t];
        float4 b2 = c4[(size_t)j2 * (DC / 4) + t];
        s1 += a.x * b1.x + a.y * b1.y + a.z * b1.z + a.w * b1.w;
        s2 += a.x * b2.x + a.y * b2.y + a.z * b2.z + a.w * b2.w;
        n0 += a.x * a.x + a.y * a.y + a.z * a.z + a.w * a.w;
        n1 += b1.x * b1.x + b1.y * b1.y + b1.z * b1.z + b1.w * b1.w;
        n2 += b2.x * b2.x + b2.y * b2.y + b2.z * b2.z + b2.w * b2.w;
    }
    for (int mm = 1; mm < 64; mm <<= 1) {
        s1 += __shfl_xor(s1, mm); s2 += __shfl_xor(s2, mm);
        n0 += __shfl_xor(n0, mm); n1 += __shfl_xor(n1, mm); n2 += __shfl_xor(n2, mm);
    }
    if (lane == 0) {
        ap1[row] = a1; ap2[row] = a2v;
        an[row] = sqrtf(__uint_as_float(mnA[row]));
        alpha1[row] = s1 / (sqrtf(n0) * sqrtf(n1));
        alpha2[row] = s2 / (sqrtf(n0) * sqrtf(n2));
    }
}

// ---------------- K7: final loss + prec ----------------
__global__ __launch_bounds__(256) void k_final(const float* __restrict__ ap1, const float* __restrict__ ap2,
                                               const float* __restrict__ an,
                                               const float* __restrict__ alpha1, const float* __restrict__ alpha2,
                                               float* __restrict__ out) {
    int tid = threadIdx.x;
    float sl11 = 0.f, sl13 = 0.f, sp = 0.f;
    for (int row = tid; row < NR; row += 256) {
        float a1 = alpha1[row], a2 = alpha2[row];
        float dap1 = ap1[row], dap2 = ap2[row], dan = an[row];
        float y = (a1 < a2) ? -1.f : 1.f;
        float ym = (a1 == a2) ? 0.f : 1.f;
        float x1 = dap2 * ym;
        float x2 = dap1 * ym + MARG * (a1 - a2 - y);
        sl11 += fmaxf(0.f, -y * (x1 - x2) + MARG);
        float ap1m = dap1 + MARG * (a1 - 1.f);
        sl13 += fmaxf(0.f, -(dan - ap1m) + MARG);
        sp += (dan > ap1m) ? 1.f : 0.f;
    }
    for (int m = 1; m < 64; m <<= 1) {
        sl11 += __shfl_xor(sl11, m);
        sl13 += __shfl_xor(sl13, m);
        sp += __shfl_xor(sp, m);
    }
    __shared__ float r11[4], r13[4], rp[4];
    if ((tid & 63) == 0) { r11[tid >> 6] = sl11; r13[tid >> 6] = sl13; rp[tid >> 6] = sp; }
    __syncthreads();
    if (tid == 0) {
        float t11 = r11[0] + r11[1] + r11[2] + r11[3];
        float t13 = r13[0] + r13[1] + r13[2] + r13[3];
        float tp = rp[0] + rp[1] + rp[2] + rp[3];
        out[0] = 0.1f * (t11 / (float)NR) + t13 / (float)NR;
        out[1] = tp / (float)NR;
    }
}

extern "C" void kernel_launch(void* const* d_in, const int* in_sizes, int n_in,
                              void* d_out, int out_size, void* d_ws, size_t ws_size,
                              hipStream_t stream) {
    const float* emb = (const float*)d_in[0];
    const int* label = (const int*)d_in[1];
    const float* clot = (const float*)d_in[2];
    float* out = (float*)d_out;

    char* ws = (char*)d_ws;
    size_t off = 0;
    auto alloc = [&](size_t bytes) -> char* {
        char* p = ws + off;
        off = (off + bytes + 255) & ~(size_t)255;
        return p;
    };
    short*    embb = (short*)alloc((size_t)NR * DE * 2);
    float*    sq   = (float*)alloc(NR * 4);
    int*      cnt  = (int*)alloc(512 * 4);
    int*      cOff = (int*)alloc(512 * 4);
    int*      fill = (int*)alloc(512 * 4);
    int*      list = (int*)alloc(NR * 4);
    unsigned* mnA  = (unsigned*)alloc((size_t)NR * 4);
    float*    ap1  = (float*)alloc(NR * 4);
    float*    ap2  = (float*)alloc(NR * 4);
    float*    an   = (float*)alloc(NR * 4);
    float*    al1  = (float*)alloc(NR * 4);
    float*    al2  = (float*)alloc(NR * 4);

    hipMemsetAsync(cnt, 0, 512 * 4, stream);
    hipMemsetAsync(fill, 0, 512 * 4, stream);
    hipMemsetAsync(mnA, 0xFF, (size_t)NR * 4, stream);   // large bits: +inf for positive-float min

    k_prep_emb<<<dim3(NR), dim3(256), 0, stream>>>(emb, label, embb, sq, cnt);
    k_scan<<<dim3(1), dim3(512), 0, stream>>>(cnt, cOff);
    k_fill<<<dim3(NR / 256), dim3(256), 0, stream>>>(label, cOff, fill, list);
    k_main<<<dim3(528), dim3(512), 0, stream>>>(embb, sq, label, mnA);
    k_pos<<<dim3(NR / 4), dim3(256), 0, stream>>>(embb, sq, clot, label, cnt, cOff, list,
                                                  mnA, ap1, ap2, an, al1, al2);
    k_final<<<dim3(1), dim3(256), 0, stream>>>(ap1, ap2, an, al1, al2, out);
}

// Round 5
// 256.909 us; speedup vs baseline: 1.0562x; 1.0562x over previous
//
#include <hip/hip_runtime.h>
#include <stdint.h>

#define NR 8192
#define DE 1024
#define DC 512
#define BIGF 9999999.0f
#define MARG 0.3f
#define NEGI -3.0e38f
#define POSI 3.0e38f

typedef __attribute__((ext_vector_type(8))) short bf16x8;
typedef __attribute__((ext_vector_type(4))) float f32x4;

typedef __attribute__((address_space(3))) unsigned int lds_u32;
typedef const __attribute__((address_space(1))) unsigned int glb_u32;

static __device__ __forceinline__ void ld_g2l16(const void* g, void* l) {
    __builtin_amdgcn_global_load_lds((glb_u32*)g, (lds_u32*)l, 16, 0, 0);
}

static __device__ __forceinline__ unsigned short f2bf(float x) {
    unsigned u = __float_as_uint(x);
    unsigned r = u + 0x7FFFu + ((u >> 16) & 1u);
    return (unsigned short)(r >> 16);
}

static __device__ __forceinline__ float b2f(short u) {
    return __uint_as_float(((unsigned)(unsigned short)u) << 16);
}

// ---------------- K1: emb -> bf16, sq[i] = ||emb_i||^2, class histogram ----------------
__global__ __launch_bounds__(256) void k_prep_emb(const float* __restrict__ emb,
                                                  const int* __restrict__ label,
                                                  short* __restrict__ embb,
                                                  float* __restrict__ sq,
                                                  int* __restrict__ cnt) {
    int row = blockIdx.x, tid = threadIdx.x;
    float4 v = ((const float4*)(emb + (size_t)row * DE))[tid];
    float s = v.x * v.x + v.y * v.y + v.z * v.z + v.w * v.w;
    ushort4 b;
    b.x = f2bf(v.x); b.y = f2bf(v.y); b.z = f2bf(v.z); b.w = f2bf(v.w);
    *(ushort4*)&embb[(size_t)row * DE + tid * 4] = b;
    for (int m = 1; m < 64; m <<= 1) s += __shfl_xor(s, m);
    __shared__ float red[4];
    if ((tid & 63) == 0) red[tid >> 6] = s;
    __syncthreads();
    if (tid == 0) {
        sq[row] = red[0] + red[1] + red[2] + red[3];
        atomicAdd(&cnt[label[row]], 1);
    }
}

// ---------------- K2: exclusive scan of class counts (512, single block) ----------------
__global__ __launch_bounds__(512) void k_scan(const int* __restrict__ cnt,
                                              int* __restrict__ clsOff) {
    __shared__ int s[512];
    int t = threadIdx.x;
    s[t] = cnt[t];
    __syncthreads();
    for (int d = 1; d < 512; d <<= 1) {
        int v = (t >= d) ? s[t - d] : 0;
        __syncthreads();
        s[t] += v;
        __syncthreads();
    }
    clsOff[t] = s[t] - cnt[t];
}

// ---------------- K3: scatter rows into class member lists ----------------
__global__ __launch_bounds__(256) void k_fill(const int* __restrict__ label,
                                              const int* __restrict__ clsOff,
                                              int* __restrict__ fill,
                                              int* __restrict__ list) {
    int i = blockIdx.x * 256 + threadIdx.x;
    int l = label[i];
    int p = atomicAdd(&fill[l], 1);
    list[clsOff[l] + p] = i;
}

// ---------------- K4: symmetric GEMM + min-of-negative row & column reductions ----------------
// 544 upper-triangular blocks: L -> (bx, pnl), pnl <= 4*bx+3; jt covers col-panels
// q = 4*bx+jt with q >= pnl. Negative side needs ONLY the min value.
// ROUND-4 DELTA vs round-0 (which measured 124.5us): exactly ONE line changed —
// XCD-chunked block remap. 544 = 8*68; dispatch round-robins wgid%8 across XCDs, so
// L = (bid&7)*68 + bid>>3 gives each XCD a contiguous run of 68 L-values. Consecutive
// L share bx -> the same <=1MB B column-panel stays resident in that XCD's 4MB L2
// instead of all 8 XCDs pulling it through L3/HBM. Pure index permutation (bijective
// on [0,544)): zero hazard surface. Tests the fetch-path/L2-locality theory in isolation.
__global__ __launch_bounds__(256, 3) void k_main(const short* __restrict__ embb,
                                                 const float* __restrict__ sq,
                                                 const int* __restrict__ label,
                                                 unsigned* __restrict__ mnA) {
    const int L = (blockIdx.x & 7) * 68 + (blockIdx.x >> 3);
    int bx = (int)((sqrtf((float)(1 + 2 * L)) - 1.0f) * 0.5f);
    while (2 * (bx + 1) * (bx + 1) + 2 * (bx + 1) <= L) ++bx;
    while (2 * bx * bx + 2 * bx > L) --bx;
    const int pnl = L - (2 * bx * bx + 2 * bx);
    const int d = pnl - bx * 4;
    const int jt0 = d > 0 ? d : 0;

    __shared__ __align__(16) short As[128 * 32];
    __shared__ __align__(16) short Bs[128 * 32];

    const int tid = threadIdx.x;
    const int lane = tid & 63;
    const int w = tid >> 6;
    const int q = lane >> 4, l15 = lane & 15;
    const int i0 = pnl * 128;

    // staging source swizzle: slot rr = tid>>2, c = tid&3 -> global chunk g
    const int srow = tid >> 2;
    const int g = (tid & 3) ^ ((tid >> 3) & 3);
    const short* gA = embb + (size_t)(i0 + srow) * DE + g * 8;
    const short* gB = embb + (size_t)(bx * 512 + jt0 * 128 + srow) * DE + g * 8;

    // fragment read swizzle (conflict-free: 2 lanes/bank)
    const int pxor = q ^ ((l15 >> 1) & 3);

    // per-row state: min over negatives (value only), carried across all jt tiles
    float rmn[8], sqi[8];
    int lia[8];
#pragma unroll
    for (int pp = 0; pp < 8; ++pp) {
        rmn[pp] = POSI;
        int rowg = i0 + w * 32 + (pp >> 2) * 16 + q * 4 + (pp & 3);
        sqi[pp] = sq[rowg]; lia[pp] = label[rowg];
    }

    auto stage = [&](int koff, const short* gBb) {
        ld_g2l16(gA + koff, &As[(size_t)tid * 8]);
        ld_g2l16(gA + (size_t)64 * DE + koff, &As[(size_t)(tid + 256) * 8]);
        ld_g2l16(gBb + koff, &Bs[(size_t)tid * 8]);
        ld_g2l16(gBb + (size_t)64 * DE + koff, &Bs[(size_t)(tid + 256) * 8]);
    };

    stage(0, gB);   // prefetch (jt0, ks=0)

    for (int jt = jt0; jt < 4; ++jt) {
        const int j0 = bx * 512 + jt * 128;
        f32x4 acc[2][8];
#pragma unroll
        for (int mi = 0; mi < 2; ++mi)
#pragma unroll
            for (int ni = 0; ni < 8; ++ni) acc[mi][ni] = (f32x4){0.f, 0.f, 0.f, 0.f};

        for (int ks = 0; ks < 32; ++ks) {
            __syncthreads();          // staging visible (vmcnt drain)
            bf16x8 af[2], bfr[8];
#pragma unroll
            for (int mi = 0; mi < 2; ++mi)
                af[mi] = *(const bf16x8*)&As[(w * 32 + mi * 16 + l15) * 32 + pxor * 8];
#pragma unroll
            for (int ni = 0; ni < 8; ++ni)
                bfr[ni] = *(const bf16x8*)&Bs[(ni * 16 + l15) * 32 + pxor * 8];
#pragma unroll
            for (int mi = 0; mi < 2; ++mi)
#pragma unroll
                for (int ni = 0; ni < 8; ++ni)
                    acc[mi][ni] = __builtin_amdgcn_mfma_f32_16x16x32_bf16(af[mi], bfr[ni], acc[mi][ni], 0, 0, 0);
            __syncthreads();          // all reads done before next staging writes
            if (ks < 31) {
                stage((ks + 1) * 32, gB);
            } else if (jt < 3) {
                gB += (size_t)128 * DE;
                stage(0, gB);         // prefetch next jt; overlaps epilogue below
            }
        }

        // ---- slim epilogue: row-min (registers) + col-min (butterfly + atomic) ----
        // Col-side on the diagonal tile double-counts the same pairs -> harmless for min.
#pragma unroll
        for (int ni = 0; ni < 8; ++ni) {
            const int cg = j0 + ni * 16 + l15;
            const float sqjv = sq[cg];
            const int lbjv = label[cg];
            float cmn = POSI;
#pragma unroll
            for (int pp = 0; pp < 8; ++pp) {
                float d2 = fmaf(-2.0f, acc[pp >> 2][ni][pp & 3], sqi[pp] + sqjv);
                d2 = fmaxf(d2, 1e-12f);
                float dn = (lia[pp] == lbjv) ? POSI : d2;
                rmn[pp] = fminf(rmn[pp], dn);
                cmn = fminf(cmn, dn);
            }
            cmn = fminf(cmn, __shfl_xor(cmn, 16));
            cmn = fminf(cmn, __shfl_xor(cmn, 32));
            if (q == 0) atomicMin(&mnA[cg], __float_as_uint(cmn));
        }
    }

    // row-side final butterfly over the 16 col-residues, once per block
#pragma unroll
    for (int pp = 0; pp < 8; ++pp) {
        float m0 = rmn[pp];
        for (int s = 1; s <= 8; s <<= 1) m0 = fminf(m0, __shfl_xor(m0, s));
        if (l15 == 0) {
            int rowg = i0 + w * 32 + (pp >> 2) * 16 + q * 4 + (pp & 3);
            atomicMin(&mnA[rowg], __float_as_uint(m0));
        }
    }
}

// ---------------- K5: exact per-row positives (top-2 over classmates) + alphas ----------------
// one wave per row. ~16 classmates: exact d2 via bf16 dot, exact top-2 with indices and
// jax top_k tie-break (lower index). Self is in the list: d(i,i)=clip floor (ranks last).
// cc==1 fallback: ref's top-2 second value = max-neg - BIG; full scan (expected never hit).
__global__ __launch_bounds__(256) void k_pos(const short* __restrict__ embb,
                                             const float* __restrict__ sq,
                                             const float* __restrict__ clot,
                                             const int* __restrict__ label,
                                             const int* __restrict__ cnt,
                                             const int* __restrict__ clsOff,
                                             const int* __restrict__ clsList,
                                             const unsigned* __restrict__ mnA,
                                             float* __restrict__ ap1, float* __restrict__ ap2,
                                             float* __restrict__ an,
                                             float* __restrict__ alpha1, float* __restrict__ alpha2) {
    int wid = threadIdx.x >> 6, lane = threadIdx.x & 63;
    int row = blockIdx.x * 4 + wid;
    int lb = label[row];
    int cc = cnt[lb], off = clsOff[lb];
    float sqiv = sq[row];

    // row chunk: lane covers dims [lane*16, lane*16+16)
    const bf16x8* rp = (const bf16x8*)(embb + (size_t)row * DE + lane * 16);
    bf16x8 ra = rp[0], rb = rp[1];
    float rf[16];
#pragma unroll
    for (int t = 0; t < 8; ++t) { rf[t] = b2f(ra[t]); rf[8 + t] = b2f(rb[t]); }

    float v1 = NEGI, v2 = NEGI;
    int i1 = 0, i2 = 0;
    for (int m = 0; m < cc; ++m) {
        int j = clsList[off + m];
        float d2;
        if (j == row) {
            d2 = 1e-12f;
        } else {
            const bf16x8* jp = (const bf16x8*)(embb + (size_t)j * DE + lane * 16);
            bf16x8 ja = jp[0], jb = jp[1];
            float s = 0.f;
#pragma unroll
            for (int t = 0; t < 8; ++t) s = fmaf(rf[t], b2f(ja[t]), s);
#pragma unroll
            for (int t = 0; t < 8; ++t) s = fmaf(rf[8 + t], b2f(jb[t]), s);
            for (int mm = 1; mm < 64; mm <<= 1) s += __shfl_xor(s, mm);
            d2 = fmaxf(fmaf(-2.0f, s, sqiv + sq[j]), 1e-12f);
        }
        bool t1 = (d2 > v1) || (d2 == v1 && j < i1);
        bool t2 = (d2 > v2) || (d2 == v2 && j < i2);
        v2 = t1 ? v1 : (t2 ? d2 : v2);
        i2 = t1 ? i1 : (t2 ? j : i2);
        v1 = t1 ? d2 : v1;
        i1 = t1 ? j : i1;
    }

    float a1 = sqrtf(v1);
    int j1 = i1;
    float a2v; int j2;
    if (cc >= 2) {
        a2v = sqrtf(v2);
        j2 = i2;
    } else {
        // singleton class: ref falls back to best (max-dist) negative - BIG
        float kv = NEGI; int ki = 0;
        for (int c = lane; c < NR; c += 64) {
            if (label[c] == lb) continue;
            float s = 0.f;
            const short* crow = embb + (size_t)c * DE;
            const short* rrow = embb + (size_t)row * DE;
            for (int t = 0; t < DE; ++t) s = fmaf(b2f(rrow[t]), b2f(crow[t]), s);
            float d2c = fmaxf(fmaf(-2.0f, s, sqiv + sq[c]), 1e-12f);
            bool tk = (d2c > kv) || (d2c == kv && c < ki);
            kv = tk ? d2c : kv; ki = tk ? c : ki;
        }
        for (int mm = 1; mm < 64; mm <<= 1) {
            float ov = __shfl_xor(kv, mm); int oi = __shfl_xor(ki, mm);
            bool tk = (ov > kv) || (ov == kv && oi < ki);
            kv = tk ? ov : kv; ki = tk ? oi : ki;
        }
        a2v = sqrtf(kv) - BIGF;
        j2 = ki;
    }

    // alpha dots + norms over clot
    const float4* c4 = (const float4*)clot;
    float s1 = 0.f, s2 = 0.f, n0 = 0.f, n1 = 0.f, n2 = 0.f;
    for (int t = lane; t < DC / 4; t += 64) {
        float4 a = c4[(size_t)row * (DC / 4) + t];
        float4 b1 = c4[(size_t)j1 * (DC / 4) + t];
        float4 b2 = c4[(size_t)j2 * (DC / 4) + t];
        s1 += a.x * b1.x + a.y * b1.y + a.z * b1.z + a.w * b1.w;
        s2 += a.x * b2.x + a.y * b2.y + a.z * b2.z + a.w * b2.w;
        n0 += a.x * a.x + a.y * a.y + a.z * a.z + a.w * a.w;
        n1 += b1.x * b1.x + b1.y * b1.y + b1.z * b1.z + b1.w * b1.w;
        n2 += b2.x * b2.x + b2.y * b2.y + b2.z * b2.z + b2.w * b2.w;
    }
    for (int mm = 1; mm < 64; mm <<= 1) {
        s1 += __shfl_xor(s1, mm); s2 += __shfl_xor(s2, mm);
        n0 += __shfl_xor(n0, mm); n1 += __shfl_xor(n1, mm); n2 += __shfl_xor(n2, mm);
    }
    if (lane == 0) {
        ap1[row] = a1; ap2[row] = a2v;
        an[row] = sqrtf(__uint_as_float(mnA[row]));
        alpha1[row] = s1 / (sqrtf(n0) * sqrtf(n1));
        alpha2[row] = s2 / (sqrtf(n0) * sqrtf(n2));
    }
}

// ---------------- K7: final loss + prec ----------------
__global__ __launch_bounds__(256) void k_final(const float* __restrict__ ap1, const float* __restrict__ ap2,
                                               const float* __restrict__ an,
                                               const float* __restrict__ alpha1, const float* __restrict__ alpha2,
                                               float* __restrict__ out) {
    int tid = threadIdx.x;
    float sl11 = 0.f, sl13 = 0.f, sp = 0.f;
    for (int row = tid; row < NR; row += 256) {
        float a1 = alpha1[row], a2 = alpha2[row];
        float dap1 = ap1[row], dap2 = ap2[row], dan = an[row];
        float y = (a1 < a2) ? -1.f : 1.f;
        float ym = (a1 == a2) ? 0.f : 1.f;
        float x1 = dap2 * ym;
        float x2 = dap1 * ym + MARG * (a1 - a2 - y);
        sl11 += fmaxf(0.f, -y * (x1 - x2) + MARG);
        float ap1m = dap1 + MARG * (a1 - 1.f);
        sl13 += fmaxf(0.f, -(dan - ap1m) + MARG);
        sp += (dan > ap1m) ? 1.f : 0.f;
    }
    for (int m = 1; m < 64; m <<= 1) {
        sl11 += __shfl_xor(sl11, m);
        sl13 += __shfl_xor(sl13, m);
        sp += __shfl_xor(sp, m);
    }
    __shared__ float r11[4], r13[4], rp[4];
    if ((tid & 63) == 0) { r11[tid >> 6] = sl11; r13[tid >> 6] = sl13; rp[tid >> 6] = sp; }
    __syncthreads();
    if (tid == 0) {
        float t11 = r11[0] + r11[1] + r11[2] + r11[3];
        float t13 = r13[0] + r13[1] + r13[2] + r13[3];
        float tp = rp[0] + rp[1] + rp[2] + rp[3];
        out[0] = 0.1f * (t11 / (float)NR) + t13 / (float)NR;
        out[1] = tp / (float)NR;
    }
}

extern "C" void kernel_launch(void* const* d_in, const int* in_sizes, int n_in,
                              void* d_out, int out_size, void* d_ws, size_t ws_size,
                              hipStream_t stream) {
    const float* emb = (const float*)d_in[0];
    const int* label = (const int*)d_in[1];
    const float* clot = (const float*)d_in[2];
    float* out = (float*)d_out;

    char* ws = (char*)d_ws;
    size_t off = 0;
    auto alloc = [&](size_t bytes) -> char* {
        char* p = ws + off;
        off = (off + bytes + 255) & ~(size_t)255;
        return p;
    };
    short*    embb = (short*)alloc((size_t)NR * DE * 2);
    float*    sq   = (float*)alloc(NR * 4);
    int*      cnt  = (int*)alloc(512 * 4);
    int*      cOff = (int*)alloc(512 * 4);
    int*      fill = (int*)alloc(512 * 4);
    int*      list = (int*)alloc(NR * 4);
    unsigned* mnA  = (unsigned*)alloc((size_t)NR * 4);
    float*    ap1  = (float*)alloc(NR * 4);
    float*    ap2  = (float*)alloc(NR * 4);
    float*    an   = (float*)alloc(NR * 4);
    float*    al1  = (float*)alloc(NR * 4);
    float*    al2  = (float*)alloc(NR * 4);

    hipMemsetAsync(cnt, 0, 512 * 4, stream);
    hipMemsetAsync(fill, 0, 512 * 4, stream);
    hipMemsetAsync(mnA, 0xFF, (size_t)NR * 4, stream);   // large bits: +inf for positive-float min

    k_prep_emb<<<dim3(NR), dim3(256), 0, stream>>>(emb, label, embb, sq, cnt);
    k_scan<<<dim3(1), dim3(512), 0, stream>>>(cnt, cOff);
    k_fill<<<dim3(NR / 256), dim3(256), 0, stream>>>(label, cOff, fill, list);
    k_main<<<dim3(544), dim3(256), 0, stream>>>(embb, sq, label, mnA);
    k_pos<<<dim3(NR / 4), dim3(256), 0, stream>>>(embb, sq, clot, label, cnt, cOff, list,
                                                  mnA, ap1, ap2, an, al1, al2);
    k_final<<<dim3(1), dim3(256), 0, stream>>>(ap1, ap2, an, al1, al2, out);
}